// Round 16
// baseline (145.520 us; speedup 1.0000x reference)
//
#include <hip/hip_runtime.h>

#define NROWS 8192
#define DDIM 128

typedef unsigned short u16;
typedef unsigned int u32;
typedef unsigned long long u64;
typedef __attribute__((ext_vector_type(4))) float f32x4;
typedef __attribute__((ext_vector_type(4), aligned(8))) float f32x4u;
typedef __attribute__((ext_vector_type(2))) float f32x2;
typedef __attribute__((ext_vector_type(4))) int i32x4;
typedef __attribute__((ext_vector_type(8))) short short8;

__device__ __forceinline__ u16 f32_to_bf16(float f){
  u32 u = __float_as_uint(f);
  u32 r = (u + 0x7FFFu + ((u >> 16) & 1u)) >> 16;
  return (u16)r;
}
__device__ __forceinline__ float bf16_to_f32(u16 h){ return __uint_as_float(((u32)h) << 16); }

// ---------------- kernel 1: split f32 -> bf16 hi/lo (fragment-packed) + sq + key init ----------------
__global__ __launch_bounds__(256) void pack_kernel(const float* __restrict__ in,
                                                   u16* __restrict__ phi, u16* __restrict__ plo,
                                                   float* __restrict__ sq,
                                                   u64* __restrict__ pos_key, u64* __restrict__ neg_key){
  int t = blockIdx.x * 256 + threadIdx.x;
  if (t < NROWS){ pos_key[t] = 0ull; neg_key[t] = 0xFFFFFFFFFFFFFFFFull; }
  int r = t >> 4, s = t & 15;                  // row, 8-elem segment
  const float* src = in + (size_t)r * DDIM + s * 8;
  f32x4 a = *(const f32x4*)(src);
  f32x4 b = *(const f32x4*)(src + 4);
  float x[8] = {a.x, a.y, a.z, a.w, b.x, b.y, b.z, b.w};
  short8 hv, lv;
  float ss = 0.f;
  #pragma unroll
  for (int j = 0; j < 8; ++j){
    u16 h = f32_to_bf16(x[j]);
    u16 l = f32_to_bf16(x[j] - bf16_to_f32(h));
    hv[j] = (short)h; lv[j] = (short)l;
    ss += x[j] * x[j];
  }
  size_t dst = (((size_t)(r >> 4) * 4 + (s >> 2)) * 64 + (s & 3) * 16 + (r & 15)) * 8;
  *(short8*)(phi + dst) = hv;
  *(short8*)(plo + dst) = lv;
  #pragma unroll
  for (int m = 1; m < 16; m <<= 1) ss += __shfl_xor(ss, m, 64);
  if (s == 0) sq[r] = ss;
}

// ---------------- kernel 2: row-panel sweep — wave owns 16 rows x 512 cols, 8 steps of 64 ----------------
__global__ __launch_bounds__(256, 3) void dist_kernel(
    const u16* __restrict__ phi, const u16* __restrict__ plo,
    const float* __restrict__ sq, const int* __restrict__ tgt,
    float* __restrict__ dist, u64* __restrict__ pos_key, u64* __restrict__ neg_key)
{
  // 2048 blocks = 512 row-groups x 4 col-quarters; XCD (id&7) owns 64 contiguous row-groups
  int id = blockIdx.x;
  int xcd = id & 7, r8 = id >> 3;            // r8 in [0,256)
  const int rg = xcd * 64 + (r8 >> 2);       // row-group (16 rows)
  const int q  = r8 & 3;                     // col quarter (2048 cols)

  const int tid = threadIdx.x;
  const int w = tid >> 6, lane = tid & 63;
  const int lr = lane & 15, g = lane >> 4;

  const int row  = rg * 16 + lr;             // this lane's output row
  const int colw = q * 2048 + w * 512;       // wave's col base

  // A fragments resident: 16 rows, kk=0..3, hi+lo  (8 x short8 = 32 VGPR)
  short8 ahi[4], alo[4];
  #pragma unroll
  for (int kk = 0; kk < 4; ++kk){
    size_t offA = ((size_t)((rg * 4 + kk) * 64) + lane) * 8;
    ahi[kk] = *(const short8*)(phi + offA);
    alo[kk] = *(const short8*)(plo + offA);
  }
  const float sqr = sq[row];
  const int   tr  = tgt[row];
  float* drow = dist + (size_t)row * NROWS;

  float bpv = -1.f, bnv = 3.0e38f; int bpc = 0x7FFFFFFF, bnc = 0x7FFFFFFF;

  // B double-buffer: per parity 4n x (hi,lo) = 8 x short8 (32 VGPR), 2 parities
  short8 bhi[2][4], blo[2][4];
  const int p00 = q * 128 + w * 32;          // first step's first panel

  #define LOADB(p, S, KK)                                              \
    _Pragma("unroll")                                                  \
    for (int n_ = 0; n_ < 4; ++n_){                                    \
      size_t off = ((size_t)(((p00 + (S) * 4 + n_) * 4 + (KK)) * 64) + lane) * 8; \
      bhi[p][n_] = *(const short8*)(phi + off);                        \
      blo[p][n_] = *(const short8*)(plo + off);                        \
    }

  LOADB(0, 0, 0);

  for (int s = 0; s < 8; ++s){
    f32x4 acc[4] = {};
    #pragma unroll
    for (int kk = 0; kk < 4; ++kk){
      const int cur = kk & 1, nxt = cur ^ 1;
      if (kk < 3){
        LOADB(nxt, s, kk + 1);
      } else if (s < 7){
        LOADB(nxt, s + 1, 0);                // nxt==0: next step starts on parity 0
      }
      #pragma unroll
      for (int n = 0; n < 4; ++n){
        acc[n] = __builtin_amdgcn_mfma_f32_16x16x32_bf16(bhi[cur][n], ahi[kk], acc[n], 0, 0, 0);
        acc[n] = __builtin_amdgcn_mfma_f32_16x16x32_bf16(blo[cur][n], ahi[kk], acc[n], 0, 0, 0);
        acc[n] = __builtin_amdgcn_mfma_f32_16x16x32_bf16(bhi[cur][n], alo[kk], acc[n], 0, 0, 0);
      }
    }
    // epilogue for this 64-col step (overlaps next step's in-flight B loads)
    const int cb0 = colw + s * 64;
    #pragma unroll
    for (int n = 0; n < 4; ++n){
      const int cb = cb0 + n * 16 + g * 4;
      f32x4 sqc = *(const f32x4*)(sq + cb);
      i32x4 tcv = *(const i32x4*)(tgt + cb);
      f32x4 dd4;
      #pragma unroll
      for (int r = 0; r < 4; ++r){
        float d2 = sqr + sqc[r] - 2.f * acc[n][r];
        d2 = fmaxf(d2, 1e-12f);
        dd4[r] = __builtin_amdgcn_sqrtf(d2);
        if (tr == tcv[r]){
          if (d2 > bpv){ bpv = d2; bpc = cb + r; }
        } else {
          if (d2 < bnv){ bnv = d2; bnc = cb + r; }
        }
      }
      *(f32x4u*)(drow + cb) = dd4;
    }
  }
  #undef LOADB

  // cross-g reduction (lanes lr, lr+16, lr+32, lr+48 share a row) + one atomic pair
  #pragma unroll
  for (int msk = 16; msk <= 32; msk <<= 1){
    float ov = __shfl_xor(bpv, msk, 64); int oc = __shfl_xor(bpc, msk, 64);
    if (ov > bpv || (ov == bpv && oc < bpc)){ bpv = ov; bpc = oc; }
    ov = __shfl_xor(bnv, msk, 64); oc = __shfl_xor(bnc, msk, 64);
    if (ov < bnv || (ov == bnv && oc < bnc)){ bnv = ov; bnc = oc; }
  }
  if (g == 0){
    if (bpv >= 0.f)
      atomicMax(&pos_key[row],
                ((u64)__float_as_uint(__builtin_amdgcn_sqrtf(bpv)) << 32) | (u64)(0xFFFFFFFFu - (u32)bpc));
    if (bnv < 3.0e38f)
      atomicMin(&neg_key[row],
                ((u64)__float_as_uint(__builtin_amdgcn_sqrtf(bnv)) << 32) | (u64)(u32)bnc);
  }
}

// ---------------- kernel 3: fused decode + gathers + hinge losses + prec (single block) ----------------
__global__ __launch_bounds__(1024) void final_kernel(const u64* __restrict__ pk, const u64* __restrict__ nk,
                                                     float* __restrict__ out){
  __shared__ float s_ap[NROWS];   // 32 KB
  __shared__ float s_an[NROWS];   // 32 KB
  int tid = threadIdx.x;
  int p2r[8], n1r[8];
  #pragma unroll
  for (int j = 0; j < 8; ++j){
    int i = tid + j * 1024;
    u64 p = pk[i], q = nk[i];
    s_ap[i] = __uint_as_float((u32)(p >> 32));
    s_an[i] = __uint_as_float((u32)(q >> 32));
    p2r[j] = (int)(0xFFFFFFFFu - (u32)(p & 0xFFFFFFFFu));
    n1r[j] = (int)(u32)(q & 0xFFFFFFFFu);
  }
  __syncthreads();
  float s1 = 0.f, s2 = 0.f, s3 = 0.f; float pc = 0.f;
  #pragma unroll
  for (int j = 0; j < 8; ++j){
    int i = tid + j * 1024;
    float a = s_ap[i], b = s_an[i];
    float n12 = s_an[n1r[j]];
    float p12 = s_ap[p2r[j]];
    s1 += fmaxf(a - b, 0.f);
    s2 += fmaxf(a - n12, 0.f);
    s3 += fmaxf(p12 - b, 0.f);
    pc += (b > a) ? 1.f : 0.f;
  }
  __syncthreads();
  float* r1 = s_ap; float* r2 = s_ap + 1024; float* r3 = s_an; float* r4 = s_an + 1024;
  r1[tid] = s1; r2[tid] = s2; r3[tid] = s3; r4[tid] = pc;
  __syncthreads();
  for (int s = 512; s > 0; s >>= 1){
    if (tid < s){ r1[tid] += r1[tid + s]; r2[tid] += r2[tid + s]; r3[tid] += r3[tid + s]; r4[tid] += r4[tid + s]; }
    __syncthreads();
  }
  if (tid == 0){
    float inv = 1.f / (float)NROWS;
    out[0] = r1[0] * inv + 0.1f * (r2[0] * inv) + 0.1f * (r3[0] * inv);
    out[1] = r4[0] * inv;
  }
}

extern "C" void kernel_launch(void* const* d_in, const int* in_sizes, int n_in,
                              void* d_out, int out_size, void* d_ws, size_t ws_size,
                              hipStream_t stream){
  const float* inputs = (const float*)d_in[0];
  const int* targets = (const int*)d_in[1];
  float* out = (float*)d_out;
  char* ws = (char*)d_ws;

  u16* phi = (u16*)ws;                                   // 2 MiB packed hi
  u16* plo = (u16*)(ws + (2u << 20));                    // 2 MiB packed lo
  float* sq = (float*)(ws + (4u << 20));                 // 32 KiB
  u64* pos_key = (u64*)(ws + (4u << 20) + (64u << 10));  // 64 KiB
  u64* neg_key = (u64*)(ws + (4u << 20) + (128u << 10)); // 64 KiB

  pack_kernel<<<(NROWS * 16) / 256, 256, 0, stream>>>(inputs, phi, plo, sq, pos_key, neg_key);
  dist_kernel<<<2048, 256, 0, stream>>>(phi, plo, sq, targets, out + 2, pos_key, neg_key);
  final_kernel<<<1, 1024, 0, stream>>>(pos_key, neg_key, out);
}

// Round 21
// 129.990 us; speedup vs baseline: 1.1195x; 1.1195x over previous
//
#include <hip/hip_runtime.h>

#define NROWS 8192
#define DDIM 128

typedef unsigned short u16;
typedef unsigned int u32;
typedef unsigned long long u64;
typedef __attribute__((ext_vector_type(4))) float f32x4;
typedef __attribute__((ext_vector_type(4), aligned(8))) float f32x4u;  // 8B-aligned vector store
typedef __attribute__((ext_vector_type(2))) float f32x2;
typedef __attribute__((ext_vector_type(4))) int i32x4;
typedef __attribute__((ext_vector_type(8))) short short8;

__device__ __forceinline__ u16 f32_to_bf16(float f){
  u32 u = __float_as_uint(f);
  u32 r = (u + 0x7FFFu + ((u >> 16) & 1u)) >> 16;
  return (u16)r;
}
__device__ __forceinline__ float bf16_to_f32(u16 h){ return __uint_as_float(((u32)h) << 16); }

// ---------------- kernel 1: split f32 -> bf16 hi/lo (fragment-packed) + sq + key init ----------------
__global__ __launch_bounds__(256) void pack_kernel(const float* __restrict__ in,
                                                   u16* __restrict__ phi, u16* __restrict__ plo,
                                                   float* __restrict__ sq,
                                                   u64* __restrict__ pos_key, u64* __restrict__ neg_key){
  int t = blockIdx.x * 256 + threadIdx.x;
  if (t < NROWS){ pos_key[t] = 0ull; neg_key[t] = 0xFFFFFFFFFFFFFFFFull; }
  int r = t >> 4, s = t & 15;                  // row, 8-elem segment
  const float* src = in + (size_t)r * DDIM + s * 8;
  f32x4 a = *(const f32x4*)(src);
  f32x4 b = *(const f32x4*)(src + 4);
  float x[8] = {a.x, a.y, a.z, a.w, b.x, b.y, b.z, b.w};
  short8 hv, lv;
  float ss = 0.f;
  #pragma unroll
  for (int j = 0; j < 8; ++j){
    u16 h = f32_to_bf16(x[j]);
    u16 l = f32_to_bf16(x[j] - bf16_to_f32(h));
    hv[j] = (short)h; lv[j] = (short)l;
    ss += x[j] * x[j];
  }
  size_t dst = (((size_t)(r >> 4) * 4 + (s >> 2)) * 64 + (s & 3) * 16 + (r & 15)) * 8;
  *(short8*)(phi + dst) = hv;
  *(short8*)(plo + dst) = lv;
  #pragma unroll
  for (int m = 1; m < 16; m <<= 1) ss += __shfl_xor(ss, m, 64);
  if (s == 0) sq[r] = ss;
}

// ---------------- kernel 2: 256x128 block tile (8 waves of 64x64), LDS-free, reg-dbuf K loop ----------------
__global__ __launch_bounds__(512, 4) void dist_kernel(
    const u16* __restrict__ phi, const u16* __restrict__ plo,
    const float* __restrict__ sq, const int* __restrict__ tgt,
    float* __restrict__ dist, u64* __restrict__ pos_key, u64* __restrict__ neg_key)
{
  // grid 2048 = 32(bi: 256-row groups) x 64(bj: 128-col tiles)
  // XCD (id&7) owns an 8(bi) x 32(bj) rectangle: operands stay L2/L3-hot
  int id = blockIdx.x;
  int xcd = id & 7, r8 = id >> 3;              // r8 in [0,256)
  int cx = xcd >> 1, cy = xcd & 1;             // 4x2 rectangles
  const int bi = cx * 8 + (r8 >> 5);
  const int bj = cy * 32 + (r8 & 31);

  const int tid = threadIdx.x;
  const int w = tid >> 6, lane = tid & 63;
  const int wr = w >> 1, wc = w & 1;           // 4x2 waves, each owns 64x64 output
  const int lr = lane & 15, g = lane >> 4;

  // acc[m][n] = mfma(B_frag, A_frag):
  //   row = bi*256 + wr*64 + m*16 + lr
  //   col = bj*128 + wc*64 + n*16 + g*4 + r
  f32x4 acc[4][4] = {};

  // register double-buffer: buf[parity][m*2 + (0=hi,1=lo)]
  short8 bufA[2][8], bufB[2][8];
  #pragma unroll
  for (int m = 0; m < 4; ++m){
    size_t offA = ((size_t)(((bi * 16 + wr * 4 + m) * 4 + 0) * 64) + lane) * 8;
    bufA[0][m * 2 + 0] = *(const short8*)(phi + offA);
    bufA[0][m * 2 + 1] = *(const short8*)(plo + offA);
    size_t offB = ((size_t)(((bj * 8 + wc * 4 + m) * 4 + 0) * 64) + lane) * 8;
    bufB[0][m * 2 + 0] = *(const short8*)(phi + offB);
    bufB[0][m * 2 + 1] = *(const short8*)(plo + offB);
  }
  #pragma unroll
  for (int kk = 0; kk < 4; ++kk){
    const int cur = kk & 1, nxt = cur ^ 1;
    if (kk < 3){
      #pragma unroll
      for (int m = 0; m < 4; ++m){
        size_t offA = ((size_t)(((bi * 16 + wr * 4 + m) * 4 + (kk + 1)) * 64) + lane) * 8;
        bufA[nxt][m * 2 + 0] = *(const short8*)(phi + offA);
        bufA[nxt][m * 2 + 1] = *(const short8*)(plo + offA);
        size_t offB = ((size_t)(((bj * 8 + wc * 4 + m) * 4 + (kk + 1)) * 64) + lane) * 8;
        bufB[nxt][m * 2 + 0] = *(const short8*)(phi + offB);
        bufB[nxt][m * 2 + 1] = *(const short8*)(plo + offB);
      }
    }
    #pragma unroll
    for (int m = 0; m < 4; ++m)
      #pragma unroll
      for (int n = 0; n < 4; ++n){
        acc[m][n] = __builtin_amdgcn_mfma_f32_16x16x32_bf16(bufB[cur][n*2+0], bufA[cur][m*2+0], acc[m][n], 0, 0, 0);
        acc[m][n] = __builtin_amdgcn_mfma_f32_16x16x32_bf16(bufB[cur][n*2+1], bufA[cur][m*2+0], acc[m][n], 0, 0, 0);
        acc[m][n] = __builtin_amdgcn_mfma_f32_16x16x32_bf16(bufB[cur][n*2+0], bufA[cur][m*2+1], acc[m][n], 0, 0, 0);
      }
  }

  // ---- epilogue: d2 -> dist (fast sqrt feeds x4 store), mining on d2 (monotone) ----
  f32x4 sqc[4]; i32x4 tcv[4]; int cbase[4];
  #pragma unroll
  for (int n = 0; n < 4; ++n){
    cbase[n] = bj * 128 + wc * 64 + n * 16 + g * 4;
    sqc[n] = *(const f32x4*)(sq + cbase[n]);
    tcv[n] = *(const i32x4*)(tgt + cbase[n]);
  }
  #pragma unroll
  for (int m = 0; m < 4; ++m){
    const int grow = bi * 256 + wr * 64 + m * 16 + lr;
    const float sqr = sq[grow];
    const int tr = tgt[grow];
    float bpv = -1.f, bnv = 3.0e38f; int bpc = 0x7FFFFFFF, bnc = 0x7FFFFFFF;
    float* drow = dist + (size_t)grow * NROWS;
    #pragma unroll
    for (int n = 0; n < 4; ++n){
      f32x4 dd4;
      #pragma unroll
      for (int r = 0; r < 4; ++r){
        float d2 = sqr + sqc[n][r] - 2.f * acc[m][n][r];
        d2 = fmaxf(d2, 1e-12f);                // upper clip 1e12 never binds for unit-normal inputs
        dd4[r] = __builtin_amdgcn_sqrtf(d2);
        if (tr == tcv[n][r]){
          if (d2 > bpv){ bpv = d2; bpc = cbase[n] + r; }
        } else {
          if (d2 < bnv){ bnv = d2; bnc = cbase[n] + r; }
        }
      }
      *(f32x4u*)(drow + cbase[n]) = dd4;       // dword-aligned x4 store
    }
    // reduce across the 4 g-groups (lanes lr, lr+16, lr+32, lr+48 hold the same row)
    #pragma unroll
    for (int msk = 16; msk <= 32; msk <<= 1){
      float ov = __shfl_xor(bpv, msk, 64); int oc = __shfl_xor(bpc, msk, 64);
      if (ov > bpv || (ov == bpv && oc < bpc)){ bpv = ov; bpc = oc; }
      ov = __shfl_xor(bnv, msk, 64); oc = __shfl_xor(bnc, msk, 64);
      if (ov < bnv || (ov == bnv && oc < bnc)){ bnv = ov; bnc = oc; }
    }
    if (g == 0){
      if (bpv >= 0.f)
        atomicMax(&pos_key[grow],
                  ((u64)__float_as_uint(__builtin_amdgcn_sqrtf(bpv)) << 32) | (u64)(0xFFFFFFFFu - (u32)bpc));
      if (bnv < 3.0e38f)
        atomicMin(&neg_key[grow],
                  ((u64)__float_as_uint(__builtin_amdgcn_sqrtf(bnv)) << 32) | (u64)(u32)bnc);
    }
  }
}

// ---------------- kernel 3: fused decode + gathers + hinge losses + prec (single block) ----------------
__global__ __launch_bounds__(1024) void final_kernel(const u64* __restrict__ pk, const u64* __restrict__ nk,
                                                     float* __restrict__ out){
  __shared__ float s_ap[NROWS];   // 32 KB
  __shared__ float s_an[NROWS];   // 32 KB
  int tid = threadIdx.x;
  int p2r[8], n1r[8];
  #pragma unroll
  for (int j = 0; j < 8; ++j){
    int i = tid + j * 1024;
    u64 p = pk[i], q = nk[i];
    s_ap[i] = __uint_as_float((u32)(p >> 32));
    s_an[i] = __uint_as_float((u32)(q >> 32));
    p2r[j] = (int)(0xFFFFFFFFu - (u32)(p & 0xFFFFFFFFu));
    n1r[j] = (int)(u32)(q & 0xFFFFFFFFu);
  }
  __syncthreads();
  float s1 = 0.f, s2 = 0.f, s3 = 0.f; float pc = 0.f;
  #pragma unroll
  for (int j = 0; j < 8; ++j){
    int i = tid + j * 1024;
    float a = s_ap[i], b = s_an[i];
    float n12 = s_an[n1r[j]];
    float p12 = s_ap[p2r[j]];
    s1 += fmaxf(a - b, 0.f);
    s2 += fmaxf(a - n12, 0.f);
    s3 += fmaxf(p12 - b, 0.f);
    pc += (b > a) ? 1.f : 0.f;
  }
  __syncthreads();
  float* r1 = s_ap; float* r2 = s_ap + 1024; float* r3 = s_an; float* r4 = s_an + 1024;
  r1[tid] = s1; r2[tid] = s2; r3[tid] = s3; r4[tid] = pc;
  __syncthreads();
  for (int s = 512; s > 0; s >>= 1){
    if (tid < s){ r1[tid] += r1[tid + s]; r2[tid] += r2[tid + s]; r3[tid] += r3[tid + s]; r4[tid] += r4[tid + s]; }
    __syncthreads();
  }
  if (tid == 0){
    float inv = 1.f / (float)NROWS;
    out[0] = r1[0] * inv + 0.1f * (r2[0] * inv) + 0.1f * (r3[0] * inv);
    out[1] = r4[0] * inv;
  }
}

extern "C" void kernel_launch(void* const* d_in, const int* in_sizes, int n_in,
                              void* d_out, int out_size, void* d_ws, size_t ws_size,
                              hipStream_t stream){
  const float* inputs = (const float*)d_in[0];
  const int* targets = (const int*)d_in[1];
  float* out = (float*)d_out;
  char* ws = (char*)d_ws;

  u16* phi = (u16*)ws;                                   // 2 MiB packed hi
  u16* plo = (u16*)(ws + (2u << 20));                    // 2 MiB packed lo
  float* sq = (float*)(ws + (4u << 20));                 // 32 KiB
  u64* pos_key = (u64*)(ws + (4u << 20) + (64u << 10));  // 64 KiB
  u64* neg_key = (u64*)(ws + (4u << 20) + (128u << 10)); // 64 KiB

  pack_kernel<<<(NROWS * 16) / 256, 256, 0, stream>>>(inputs, phi, plo, sq, pos_key, neg_key);
  dist_kernel<<<2048, 512, 0, stream>>>(phi, plo, sq, targets, out + 2, pos_key, neg_key);
  final_kernel<<<1, 1024, 0, stream>>>(pos_key, neg_key, out);
}

// Round 22
// 127.178 us; speedup vs baseline: 1.1442x; 1.0221x over previous
//
#include <hip/hip_runtime.h>

#define NROWS 8192
#define DDIM 128

typedef unsigned short u16;
typedef unsigned int u32;
typedef unsigned long long u64;
typedef __attribute__((ext_vector_type(4))) float f32x4;
typedef __attribute__((ext_vector_type(4), aligned(8))) float f32x4u;  // 8B-aligned vector store
typedef __attribute__((ext_vector_type(2))) float f32x2;
typedef __attribute__((ext_vector_type(4))) int i32x4;
typedef __attribute__((ext_vector_type(8))) short short8;

__device__ __forceinline__ u16 f32_to_bf16(float f){
  u32 u = __float_as_uint(f);
  u32 r = (u + 0x7FFFu + ((u >> 16) & 1u)) >> 16;
  return (u16)r;
}
__device__ __forceinline__ float bf16_to_f32(u16 h){ return __uint_as_float(((u32)h) << 16); }

// ---------------- kernel 1: split f32 -> bf16 hi/lo (fragment-packed) + sq + key init ----------------
__global__ __launch_bounds__(256) void pack_kernel(const float* __restrict__ in,
                                                   u16* __restrict__ phi, u16* __restrict__ plo,
                                                   float* __restrict__ sq,
                                                   u64* __restrict__ pos_key, u64* __restrict__ neg_key){
  int t = blockIdx.x * 256 + threadIdx.x;
  if (t < NROWS){ pos_key[t] = 0ull; neg_key[t] = 0xFFFFFFFFFFFFFFFFull; }
  int r = t >> 4, s = t & 15;                  // row, 8-elem segment
  const float* src = in + (size_t)r * DDIM + s * 8;
  f32x4 a = *(const f32x4*)(src);
  f32x4 b = *(const f32x4*)(src + 4);
  float x[8] = {a.x, a.y, a.z, a.w, b.x, b.y, b.z, b.w};
  short8 hv, lv;
  float ss = 0.f;
  #pragma unroll
  for (int j = 0; j < 8; ++j){
    u16 h = f32_to_bf16(x[j]);
    u16 l = f32_to_bf16(x[j] - bf16_to_f32(h));
    hv[j] = (short)h; lv[j] = (short)l;
    ss += x[j] * x[j];
  }
  size_t dst = (((size_t)(r >> 4) * 4 + (s >> 2)) * 64 + (s & 3) * 16 + (r & 15)) * 8;
  *(short8*)(phi + dst) = hv;
  *(short8*)(plo + dst) = lv;
  #pragma unroll
  for (int m = 1; m < 16; m <<= 1) ss += __shfl_xor(ss, m, 64);
  if (s == 0) sq[r] = ss;
}

// ---------------- kernel 2: LDS-free MFMA distance, reg-dbuf K loop, 3 blocks/CU ----------------
__global__ __launch_bounds__(256, 3) void dist_kernel(
    const u16* __restrict__ phi, const u16* __restrict__ plo,
    const float* __restrict__ sq, const int* __restrict__ tgt,
    float* __restrict__ dist, u64* __restrict__ pos_key, u64* __restrict__ neg_key)
{
  // 2D-chunked XCD swizzle: each XCD (id%8) owns a 16(bi) x 32(bj) rectangle
  int id = blockIdx.x;
  int xcd = id & 7, r9 = id >> 3;
  int cx = xcd >> 1, cy = xcd & 1;
  const int bi = cx * 16 + (r9 >> 5);
  const int bj = cy * 32 + (r9 & 31);

  const int tid = threadIdx.x;
  const int w = tid >> 6, lane = tid & 63;
  const int wr = w >> 1, wc = w & 1;           // 2x2 waves, each owns 64x64 output
  const int lr = lane & 15, g = lane >> 4;

  // acc[m][n] = mfma(B_frag, A_frag):
  //   row = bi*128 + wr*64 + m*16 + lr
  //   col = bj*128 + wc*64 + n*16 + g*4 + r
  f32x4 acc[4][4] = {};

  // register double-buffer: buf[parity][m*2 + (0=hi,1=lo)]
  short8 bufA[2][8], bufB[2][8];
  #pragma unroll
  for (int m = 0; m < 4; ++m){
    size_t offA = ((size_t)(((bi * 8 + wr * 4 + m) * 4 + 0) * 64) + lane) * 8;
    bufA[0][m * 2 + 0] = *(const short8*)(phi + offA);
    bufA[0][m * 2 + 1] = *(const short8*)(plo + offA);
    size_t offB = ((size_t)(((bj * 8 + wc * 4 + m) * 4 + 0) * 64) + lane) * 8;
    bufB[0][m * 2 + 0] = *(const short8*)(phi + offB);
    bufB[0][m * 2 + 1] = *(const short8*)(plo + offB);
  }
  #pragma unroll
  for (int kk = 0; kk < 4; ++kk){
    const int cur = kk & 1, nxt = cur ^ 1;
    if (kk < 3){
      #pragma unroll
      for (int m = 0; m < 4; ++m){
        size_t offA = ((size_t)(((bi * 8 + wr * 4 + m) * 4 + (kk + 1)) * 64) + lane) * 8;
        bufA[nxt][m * 2 + 0] = *(const short8*)(phi + offA);
        bufA[nxt][m * 2 + 1] = *(const short8*)(plo + offA);
        size_t offB = ((size_t)(((bj * 8 + wc * 4 + m) * 4 + (kk + 1)) * 64) + lane) * 8;
        bufB[nxt][m * 2 + 0] = *(const short8*)(phi + offB);
        bufB[nxt][m * 2 + 1] = *(const short8*)(plo + offB);
      }
    }
    #pragma unroll
    for (int m = 0; m < 4; ++m)
      #pragma unroll
      for (int n = 0; n < 4; ++n){
        acc[m][n] = __builtin_amdgcn_mfma_f32_16x16x32_bf16(bufB[cur][n*2+0], bufA[cur][m*2+0], acc[m][n], 0, 0, 0);
        acc[m][n] = __builtin_amdgcn_mfma_f32_16x16x32_bf16(bufB[cur][n*2+1], bufA[cur][m*2+0], acc[m][n], 0, 0, 0);
        acc[m][n] = __builtin_amdgcn_mfma_f32_16x16x32_bf16(bufB[cur][n*2+0], bufA[cur][m*2+1], acc[m][n], 0, 0, 0);
      }
  }

  // ---- epilogue: d2 -> dist (fast sqrt feeds x4 store), mining on d2 (monotone) ----
  f32x4 sqc[4]; i32x4 tcv[4]; int cbase[4];
  #pragma unroll
  for (int n = 0; n < 4; ++n){
    cbase[n] = bj * 128 + wc * 64 + n * 16 + g * 4;
    sqc[n] = *(const f32x4*)(sq + cbase[n]);
    tcv[n] = *(const i32x4*)(tgt + cbase[n]);
  }
  #pragma unroll
  for (int m = 0; m < 4; ++m){
    const int grow = bi * 128 + wr * 64 + m * 16 + lr;
    const float sqr = sq[grow];
    const int tr = tgt[grow];
    float bpv = -1.f, bnv = 3.0e38f; int bpc = 0x7FFFFFFF, bnc = 0x7FFFFFFF;
    float* drow = dist + (size_t)grow * NROWS;
    #pragma unroll
    for (int n = 0; n < 4; ++n){
      f32x4 dd4;
      #pragma unroll
      for (int r = 0; r < 4; ++r){
        float d2 = sqr + sqc[n][r] - 2.f * acc[m][n][r];
        d2 = fmaxf(d2, 1e-12f);                // upper clip 1e12 never binds for unit-normal inputs
        dd4[r] = __builtin_amdgcn_sqrtf(d2);
        if (tr == tcv[n][r]){
          if (d2 > bpv){ bpv = d2; bpc = cbase[n] + r; }
        } else {
          if (d2 < bnv){ bnv = d2; bnc = cbase[n] + r; }
        }
      }
      *(f32x4u*)(drow + cbase[n]) = dd4;       // dword-aligned x4 store
    }
    // reduce across the 4 g-groups (lanes lr, lr+16, lr+32, lr+48 hold the same row)
    #pragma unroll
    for (int msk = 16; msk <= 32; msk <<= 1){
      float ov = __shfl_xor(bpv, msk, 64); int oc = __shfl_xor(bpc, msk, 64);
      if (ov > bpv || (ov == bpv && oc < bpc)){ bpv = ov; bpc = oc; }
      ov = __shfl_xor(bnv, msk, 64); oc = __shfl_xor(bnc, msk, 64);
      if (ov < bnv || (ov == bnv && oc < bnc)){ bnv = ov; bnc = oc; }
    }
    if (g == 0){
      if (bpv >= 0.f)
        atomicMax(&pos_key[grow],
                  ((u64)__float_as_uint(__builtin_amdgcn_sqrtf(bpv)) << 32) | (u64)(0xFFFFFFFFu - (u32)bpc));
      if (bnv < 3.0e38f)
        atomicMin(&neg_key[grow],
                  ((u64)__float_as_uint(__builtin_amdgcn_sqrtf(bnv)) << 32) | (u64)(u32)bnc);
    }
  }
}

// ---------------- kernel 3: fused decode + gathers + hinge losses + prec (single block) ----------------
__global__ __launch_bounds__(1024) void final_kernel(const u64* __restrict__ pk, const u64* __restrict__ nk,
                                                     float* __restrict__ out){
  __shared__ float s_ap[NROWS];   // 32 KB
  __shared__ float s_an[NROWS];   // 32 KB
  int tid = threadIdx.x;
  int p2r[8], n1r[8];
  #pragma unroll
  for (int j = 0; j < 8; ++j){
    int i = tid + j * 1024;
    u64 p = pk[i], q = nk[i];
    s_ap[i] = __uint_as_float((u32)(p >> 32));
    s_an[i] = __uint_as_float((u32)(q >> 32));
    p2r[j] = (int)(0xFFFFFFFFu - (u32)(p & 0xFFFFFFFFu));
    n1r[j] = (int)(u32)(q & 0xFFFFFFFFu);
  }
  __syncthreads();
  float s1 = 0.f, s2 = 0.f, s3 = 0.f; float pc = 0.f;
  #pragma unroll
  for (int j = 0; j < 8; ++j){
    int i = tid + j * 1024;
    float a = s_ap[i], b = s_an[i];
    float n12 = s_an[n1r[j]];
    float p12 = s_ap[p2r[j]];
    s1 += fmaxf(a - b, 0.f);
    s2 += fmaxf(a - n12, 0.f);
    s3 += fmaxf(p12 - b, 0.f);
    pc += (b > a) ? 1.f : 0.f;
  }
  __syncthreads();
  float* r1 = s_ap; float* r2 = s_ap + 1024; float* r3 = s_an; float* r4 = s_an + 1024;
  r1[tid] = s1; r2[tid] = s2; r3[tid] = s3; r4[tid] = pc;
  __syncthreads();
  for (int s = 512; s > 0; s >>= 1){
    if (tid < s){ r1[tid] += r1[tid + s]; r2[tid] += r2[tid + s]; r3[tid] += r3[tid + s]; r4[tid] += r4[tid + s]; }
    __syncthreads();
  }
  if (tid == 0){
    float inv = 1.f / (float)NROWS;
    out[0] = r1[0] * inv + 0.1f * (r2[0] * inv) + 0.1f * (r3[0] * inv);
    out[1] = r4[0] * inv;
  }
}

extern "C" void kernel_launch(void* const* d_in, const int* in_sizes, int n_in,
                              void* d_out, int out_size, void* d_ws, size_t ws_size,
                              hipStream_t stream){
  const float* inputs = (const float*)d_in[0];
  const int* targets = (const int*)d_in[1];
  float* out = (float*)d_out;
  char* ws = (char*)d_ws;

  u16* phi = (u16*)ws;                                   // 2 MiB packed hi
  u16* plo = (u16*)(ws + (2u << 20));                    // 2 MiB packed lo
  float* sq = (float*)(ws + (4u << 20));                 // 32 KiB
  u64* pos_key = (u64*)(ws + (4u << 20) + (64u << 10));  // 64 KiB
  u64* neg_key = (u64*)(ws + (4u << 20) + (128u << 10)); // 64 KiB

  pack_kernel<<<(NROWS * 16) / 256, 256, 0, stream>>>(inputs, phi, plo, sq, pos_key, neg_key);
  dist_kernel<<<64 * 64, 256, 0, stream>>>(phi, plo, sq, targets, out + 2, pos_key, neg_key);
  final_kernel<<<1, 1024, 0, stream>>>(pos_key, neg_key, out);
}